// Round 9
// baseline (304.456 us; speedup 1.0000x reference)
//
#include <hip/hip_runtime.h>

// ---------------- problem constants ----------------
// B=8, T=32, S=256, DV=1024, NH=16, dh=64, DA=512, L2=2048
// video_x: [8, 8192, 1024] f32   audio_x: [8, 2048, 512] f32
// out: [8, 32, 2048] f32
//
// MEASURED (R3-R8): occupancy lever exhausted -- 2 blocks never co-reside
// (R5/R6/R7), single 1024-thr block reaches 16 waves/CU (R8) yet k1 stays
// ~220us at VALUBusy 32%. Limiter = lockstep structure: 2 barriers/chunk,
// phase A->p_lds->phase C dependency, 16x LDS re-read, 6-deep shuffle chains.
// This round: FUSED phase A+C per wave (head-pair + row-group), x consumed
// from registers, all-lane butterfly+exp, ONE barrier/chunk, 8x LDS amp.
//
// Pipeline (all f32):
//  qf = probe@wqT+bq ; qwt[d][h] = (1/8)*sum_{e in h} qf[e]*wk[e][d] ; qbs[h]
//  k1: per (b,t): p[s][h]=exp(x[s,:].qwt[:,h]+qbs[h]); ctxx[h][d]=sum_s p*x /l
//  G1: ctx_part = ctxx(head-block) @ wv^T         (K-split 2 -> ctxp)
//  G2: pool_part = (ctxp0+ctxp1+bv) @ wo^T        (K-split 2 -> poolp)
//  LN: lno = LN(poolp0+poolp1+bo)
//  G3: vt_part = lno @ pw^T                       (K-split 2 -> vtp)
//  sim: (norm(vtp0+vtp1+pb) . norm(audio)) * exp(ls) + lb

// ---- ws layout (float offsets), 23.1 MB ----
#define FB_QWT    0u
#define FB_QB     16384u
#define FB_QF     16400u
#define FB_CTXX   18432u                   // [256][16][1024]
#define FB_CTXP   4212736u
#define FB_POOLP  4737024u
#define FB_LNO    5261312u
#define FB_VTP    5523456u
#define FB_FLOATS 5785600u

// ---------------- K0a: q_flat[e] = probe . wq[e,:] + bq[e] ----------------
__global__ __launch_bounds__(256) void k_qflat(const float* __restrict__ probe,
                                               const float* __restrict__ wq,
                                               const float* __restrict__ bq,
                                               float* __restrict__ qf) {
    int e = blockIdx.x, tid = threadIdx.x;
    const float* wr = wq + (size_t)e * 1024;
    float s = 0.f;
    for (int k = tid; k < 1024; k += 256) s += probe[k] * wr[k];
    s += __shfl_xor(s, 1);  s += __shfl_xor(s, 2);  s += __shfl_xor(s, 4);
    s += __shfl_xor(s, 8);  s += __shfl_xor(s, 16); s += __shfl_xor(s, 32);
    __shared__ float sm[4];
    if ((tid & 63) == 0) sm[tid >> 6] = s;
    __syncthreads();
    if (tid == 0) qf[e] = sm[0] + sm[1] + sm[2] + sm[3] + bq[e];
}

// ---------------- K0b: qwt[d][h] = (1/8) * sum_{e in h} qf[e]*wk[e][d] ----------------
__global__ __launch_bounds__(64) void k_qwt(const float* __restrict__ qf,
                                            const float* __restrict__ wk,
                                            const float* __restrict__ bk,
                                            float* __restrict__ qwt,
                                            float* __restrict__ qbs) {
    int kc = blockIdx.x, h = blockIdx.y, tid = threadIdx.x; // 64 threads = 1 wave
    int d = kc * 64 + tid;
    float s = 0.f;
    for (int e0 = 0; e0 < 64; ++e0) {
        int e = h * 64 + e0;
        s += qf[e] * wk[(size_t)e * 1024 + d];
    }
    qwt[d * 16 + h] = s * 0.125f;
    if (kc == 0) {
        float p = qf[h * 64 + tid] * bk[h * 64 + tid];
        p += __shfl_xor(p, 1);  p += __shfl_xor(p, 2);  p += __shfl_xor(p, 4);
        p += __shfl_xor(p, 8);  p += __shfl_xor(p, 16); p += __shfl_xor(p, 32);
        if (tid == 0) qbs[h] = p * 0.125f;
    }
}

// ---------------- K1: fused scores+softmax+weighted-sum, single barrier/chunk ----
// 1024 threads (16 waves = 4/SIMD). Wave w: row-group g=w>>3 (4 rows of the
// 8-row chunk), head pair {w&7, (w&7)+8}. Per row: read row once (4xb128),
// dual dot (32 FMA), 6-level butterfly on both scores (all lanes get totals),
// exp on all lanes, acc += p*x from REGISTERS. No p_lds, no phase C.
// Row-group partials merged once at the end via xs scratch.
__global__ __launch_bounds__(1024, 1) void k1_attn(const float* __restrict__ x,
                                                   const float* __restrict__ qwt,
                                                   const float* __restrict__ qbs,
                                                   float* __restrict__ ctxx) {
    __shared__ __align__(16) float xs[2][8][1024];   // 64 KB; reused as merge scratch
    __shared__ float l_lds[16];

    const int tid  = threadIdx.x;
    const int lane = tid & 63;
    const int w    = tid >> 6;          // wave 0..15
    const int g    = w >> 3;            // row-group 0/1 (rows g*4..g*4+3)
    const int hA   = w & 7;             // heads hA and hA+8
    const int bt   = blockIdx.x;
    const float* xb = x + (size_t)bt * 262144;

    // qw[4j+i] = qwt[(lane*4 + 256*j + i)*16 + h]  (16+16 VGPRs)
    float qwA[16], qwB[16];
#pragma unroll
    for (int j = 0; j < 4; ++j)
#pragma unroll
        for (int i = 0; i < 4; ++i) {
            int d = (lane << 2) + (j << 8) + i;
            qwA[j * 4 + i] = qwt[d * 16 + hA];
            qwB[j * 4 + i] = qwt[d * 16 + hA + 8];
        }
    const float qbA = qbs[hA], qbB = qbs[hA + 8];

    float4 accA[4], accB[4];
#pragma unroll
    for (int i = 0; i < 4; ++i) {
        accA[i] = make_float4(0.f, 0.f, 0.f, 0.f);
        accB[i] = make_float4(0.f, 0.f, 0.f, 0.f);
    }
    float lA = 0.f, lB = 0.f;

    // prologue: chunk 0 (8 rows = 2048 float4), 2 f4/thread
    float4 st[2];
#pragma unroll
    for (int i = 0; i < 2; ++i)
        st[i] = *(const float4*)(xb + (size_t)(tid + i * 1024) * 4);

    for (int c = 0; c < 32; ++c) {
        const int cur = c & 1;
        float4* xw = (float4*)&xs[cur][0][0];
#pragma unroll
        for (int i = 0; i < 2; ++i) xw[tid + i * 1024] = st[i];
        __syncthreads();                  // single barrier per chunk (dbuf-safe)
        if (c < 31) {                     // prefetch next chunk during compute
            const float* nb = xb + (size_t)(c + 1) * 8192;
#pragma unroll
            for (int i = 0; i < 2; ++i)
                st[i] = *(const float4*)(nb + (size_t)(tid + i * 1024) * 4);
        }
#pragma unroll
        for (int rr = 0; rr < 4; ++rr) {
            const float* xr = &xs[cur][g * 4 + rr][0];
            float4 a0 = *(const float4*)&xr[(lane << 2)];
            float4 a1 = *(const float4*)&xr[(lane << 2) + 256];
            float4 a2 = *(const float4*)&xr[(lane << 2) + 512];
            float4 a3 = *(const float4*)&xr[(lane << 2) + 768];
            float sA = a0.x * qwA[0]  + a0.y * qwA[1]  + a0.z * qwA[2]  + a0.w * qwA[3]
                     + a1.x * qwA[4]  + a1.y * qwA[5]  + a1.z * qwA[6]  + a1.w * qwA[7]
                     + a2.x * qwA[8]  + a2.y * qwA[9]  + a2.z * qwA[10] + a2.w * qwA[11]
                     + a3.x * qwA[12] + a3.y * qwA[13] + a3.z * qwA[14] + a3.w * qwA[15];
            float sB = a0.x * qwB[0]  + a0.y * qwB[1]  + a0.z * qwB[2]  + a0.w * qwB[3]
                     + a1.x * qwB[4]  + a1.y * qwB[5]  + a1.z * qwB[6]  + a1.w * qwB[7]
                     + a2.x * qwB[8]  + a2.y * qwB[9]  + a2.z * qwB[10] + a2.w * qwB[11]
                     + a3.x * qwB[12] + a3.y * qwB[13] + a3.z * qwB[14] + a3.w * qwB[15];
            // independent butterfly chains; every lane ends with the full sum
            sA += __shfl_xor(sA, 32); sB += __shfl_xor(sB, 32);
            sA += __shfl_xor(sA, 16); sB += __shfl_xor(sB, 16);
            sA += __shfl_xor(sA, 8);  sB += __shfl_xor(sB, 8);
            sA += __shfl_xor(sA, 4);  sB += __shfl_xor(sB, 4);
            sA += __shfl_xor(sA, 2);  sB += __shfl_xor(sB, 2);
            sA += __shfl_xor(sA, 1);  sB += __shfl_xor(sB, 1);
            // scores ~|0.05| -> exp with shift 0 numerically safe here
            float pA = __expf(sA + qbA);
            float pB = __expf(sB + qbB);
            lA += pA; lB += pB;
            accA[0].x += pA * a0.x; accA[0].y += pA * a0.y; accA[0].z += pA * a0.z; accA[0].w += pA * a0.w;
            accA[1].x += pA * a1.x; accA[1].y += pA * a1.y; accA[1].z += pA * a1.z; accA[1].w += pA * a1.w;
            accA[2].x += pA * a2.x; accA[2].y += pA * a2.y; accA[2].z += pA * a2.z; accA[2].w += pA * a2.w;
            accA[3].x += pA * a3.x; accA[3].y += pA * a3.y; accA[3].z += pA * a3.z; accA[3].w += pA * a3.w;
            accB[0].x += pB * a0.x; accB[0].y += pB * a0.y; accB[0].z += pB * a0.z; accB[0].w += pB * a0.w;
            accB[1].x += pB * a1.x; accB[1].y += pB * a1.y; accB[1].z += pB * a1.z; accB[1].w += pB * a1.w;
            accB[2].x += pB * a2.x; accB[2].y += pB * a2.y; accB[2].z += pB * a2.z; accB[2].w += pB * a2.w;
            accB[3].x += pB * a3.x; accB[3].y += pB * a3.y; accB[3].z += pB * a3.z; accB[3].w += pB * a3.w;
        }
    }

    // merge the two row-group partials (wave w <-> wave w^8) via xs scratch
    __syncthreads();                      // all compute done; xs free
    float* scr = &xs[0][0][0];
    float4* s4 = (float4*)(scr + (size_t)hA * 2048);   // 8 pairs x 2048 floats = 64 KB
    if (g == 1) {
#pragma unroll
        for (int j = 0; j < 4; ++j) s4[j * 64 + lane] = accA[j];
#pragma unroll
        for (int j = 0; j < 4; ++j) s4[(4 + j) * 64 + lane] = accB[j];
        if (lane == 0) { l_lds[hA] = lA; l_lds[hA + 8] = lB; }
    }
    __syncthreads();
    if (g == 0) {
        float linvA = 1.0f / (lA + l_lds[hA]);
        float linvB = 1.0f / (lB + l_lds[hA + 8]);
        float* ob = ctxx + (size_t)bt * 16384;
#pragma unroll
        for (int j = 0; j < 4; ++j) {
            float4 o = accA[j];
            float4 q = s4[j * 64 + lane];
            o.x = (o.x + q.x) * linvA; o.y = (o.y + q.y) * linvA;
            o.z = (o.z + q.z) * linvA; o.w = (o.w + q.w) * linvA;
            *(float4*)(ob + hA * 1024 + j * 256 + (lane << 2)) = o;
        }
#pragma unroll
        for (int j = 0; j < 4; ++j) {
            float4 o = accB[j];
            float4 q = s4[(4 + j) * 64 + lane];
            o.x = (o.x + q.x) * linvB; o.y = (o.y + q.y) * linvB;
            o.z = (o.z + q.z) * linvB; o.w = (o.w + q.w) * linvB;
            *(float4*)(ob + (hA + 8) * 1024 + j * 256 + (lane << 2)) = o;
        }
    }
}

// ---------------- K-split GEMM: outp[ks][r][e] = A_row(r)[koff:+512] . B[e, koff:+512] ----
// tile 16 rows x 64 cols, 256 threads, K-slice 512 (8 kc-steps of 64).
// FOLD=0: A_eff = A0
// FOLD=1: A_eff = A0 + A1 + biask (K-dim bias folded)
template<int FOLD>
__global__ __launch_bounds__(256, 2) void k_gemm2(const float* __restrict__ A0,
                                                  const float* __restrict__ A1,
                                                  const float* __restrict__ biask,
                                                  const float* __restrict__ Bw,
                                                  float* __restrict__ outp,
                                                  unsigned a_rstride, unsigned a_cstride,
                                                  unsigned ostride) {
    __shared__ __align__(16) float a_s[16][68];
    __shared__ __align__(16) float b_s[64][68];   // col-f4 swizzled: cs=(k4+e/4)&15
    const int tid = threadIdx.x;
    const int rc = blockIdx.x;     // row-chunk (16 rows)
    const int cb = blockIdx.y;     // col-block (64 cols)
    const int ks = blockIdx.z;     // K-split 0,1
    const int koff = ks * 512;
    const int rr = tid >> 4;       // output row 0..15
    const int ee = tid & 15;       // output cols ee*4..+3

    const size_t abase = (size_t)(rc * 16 + rr) * a_rstride + (size_t)cb * a_cstride + koff;

    float ac0 = 0.f, ac1 = 0.f, ac2 = 0.f, ac3 = 0.f;

    for (int kc = 0; kc < 8; ++kc) {
        __syncthreads();
        {   // stage A: 1 float4/thread
            float4 av = *(const float4*)(A0 + abase + kc * 64 + ee * 4);
            if (FOLD == 1) {
                float4 a1 = *(const float4*)(A1 + abase + kc * 64 + ee * 4);
                float4 bk4 = *(const float4*)(biask + koff + kc * 64 + ee * 4);
                av.x += a1.x + bk4.x; av.y += a1.y + bk4.y;
                av.z += a1.z + bk4.z; av.w += a1.w + bk4.w;
            }
            *(float4*)&a_s[rr][ee * 4] = av;
        }
        // stage B: 4 float4/thread, linear global -> swizzled LDS
#pragma unroll
        for (int i = 0; i < 4; ++i) {
            int f4i = tid + i * 256;
            int e = f4i >> 4, k4 = f4i & 15;
            float4 bv4 = *(const float4*)(Bw + (size_t)(cb * 64 + e) * 1024 + koff + kc * 64 + k4 * 4);
            int cs = (k4 + (e >> 2)) & 15;
            *(float4*)&b_s[e][cs * 4] = bv4;
        }
        __syncthreads();
#pragma unroll
        for (int k4 = 0; k4 < 16; ++k4) {
            float4 av = *(const float4*)&a_s[rr][k4 * 4];
            int cs = (k4 + ee) & 15;
            float4 b0 = *(const float4*)&b_s[ee * 4 + 0][cs * 4];
            float4 b1 = *(const float4*)&b_s[ee * 4 + 1][cs * 4];
            float4 b2 = *(const float4*)&b_s[ee * 4 + 2][cs * 4];
            float4 b3 = *(const float4*)&b_s[ee * 4 + 3][cs * 4];
            ac0 += av.x * b0.x + av.y * b0.y + av.z * b0.z + av.w * b0.w;
            ac1 += av.x * b1.x + av.y * b1.y + av.z * b1.z + av.w * b1.w;
            ac2 += av.x * b2.x + av.y * b2.y + av.z * b2.z + av.w * b2.w;
            ac3 += av.x * b3.x + av.y * b3.y + av.z * b3.z + av.w * b3.w;
        }
    }
    float4 o = make_float4(ac0, ac1, ac2, ac3);
    *(float4*)(outp + (size_t)ks * 256 * ostride + (size_t)(rc * 16 + rr) * ostride + cb * 64 + ee * 4) = o;
}

// ---------------- LayerNorm over D=1024, folds poolp0+poolp1+bo ----------------
__global__ __launch_bounds__(256) void k_ln(const float* __restrict__ poolp,
                                            const float* __restrict__ bo,
                                            const float* __restrict__ g,
                                            const float* __restrict__ bb,
                                            float* __restrict__ out) {
    __shared__ float sm[8];
    int row = blockIdx.x, tid = threadIdx.x;
    float4 v0 = *(const float4*)(poolp + (size_t)row * 1024 + tid * 4);
    float4 v1 = *(const float4*)(poolp + 262144u + (size_t)row * 1024 + tid * 4);
    float4 bv = *(const float4*)(bo + tid * 4);
    float4 v;
    v.x = v0.x + v1.x + bv.x; v.y = v0.y + v1.y + bv.y;
    v.z = v0.z + v1.z + bv.z; v.w = v0.w + v1.w + bv.w;
    float s = v.x + v.y + v.z + v.w;
    float q = v.x * v.x + v.y * v.y + v.z * v.z + v.w * v.w;
    s += __shfl_xor(s, 1);  q += __shfl_xor(q, 1);
    s += __shfl_xor(s, 2);  q += __shfl_xor(q, 2);
    s += __shfl_xor(s, 4);  q += __shfl_xor(q, 4);
    s += __shfl_xor(s, 8);  q += __shfl_xor(q, 8);
    s += __shfl_xor(s, 16); q += __shfl_xor(q, 16);
    s += __shfl_xor(s, 32); q += __shfl_xor(q, 32);
    if ((tid & 63) == 0) { sm[tid >> 6] = s; sm[4 + (tid >> 6)] = q; }
    __syncthreads();
    float S = sm[0] + sm[1] + sm[2] + sm[3];
    float Q = sm[4] + sm[5] + sm[6] + sm[7];
    float mu = S * (1.f / 1024.f);
    float var = Q * (1.f / 1024.f) - mu * mu;
    float rs = rsqrtf(var + 1e-6f);
    float4 gg = *(const float4*)(g + tid * 4);
    float4 be = *(const float4*)(bb + tid * 4);
    float4 o;
    o.x = (v.x - mu) * rs * gg.x + be.x;
    o.y = (v.y - mu) * rs * gg.y + be.y;
    o.z = (v.z - mu) * rs * gg.z + be.z;
    o.w = (v.w - mu) * rs * gg.w + be.w;
    *(float4*)(out + (size_t)row * 1024 + tid * 4) = o;
}

// ---------------- sim = (vt_hat . a_hat) * exp(ls) + lb ----------------
// folds vtp0+vtp1+pb; block: 32 vt rows x 64 audio rows; grid (32,8)
__global__ __launch_bounds__(256, 2) void k_sim(const float* __restrict__ vtp,
                                                const float* __restrict__ pb,
                                                const float* __restrict__ audio,
                                                const float* __restrict__ ls,
                                                const float* __restrict__ lb,
                                                float* __restrict__ out) {
    __shared__ float a_s[64][65];
    __shared__ float v_s[32][65];
    __shared__ float rinv_a[64];
    __shared__ float rinv_v[32];
    const int tid = threadIdx.x;
    const int lc = blockIdx.x;   // 0..31
    const int b  = blockIdx.y;   // 0..7
    const int al = tid >> 2, ak = (tid & 3) * 16;
    const int vl = tid >> 3, vk = (tid & 7) * 8;
    const int rg = tid >> 4, lg = tid & 15;
    float ssa = 0.f, ssv = 0.f;
    float c00=0,c01=0,c02=0,c03=0,c10=0,c11=0,c12=0,c13=0;

    for (int kc = 0; kc < 8; ++kc) {
        __syncthreads();
        {
            const float* ap = audio + (size_t)b * 1048576 + (size_t)(lc * 64 + al) * 512 + kc * 64 + ak;
#pragma unroll
            for (int i = 0; i < 4; ++i) {
                float4 wv4 = *(const float4*)(ap + i * 4);
                ssa += wv4.x * wv4.x + wv4.y * wv4.y + wv4.z * wv4.z + wv4.w * wv4.w;
                a_s[al][ak + i * 4 + 0] = wv4.x; a_s[al][ak + i * 4 + 1] = wv4.y;
                a_s[al][ak + i * 4 + 2] = wv4.z; a_s[al][ak + i * 4 + 3] = wv4.w;
            }
            const size_t voff = (size_t)(b * 32 + vl) * 512 + kc * 64 + vk;
#pragma unroll
            for (int i = 0; i < 2; ++i) {
                float4 p0 = *(const float4*)(vtp + voff + i * 4);
                float4 p1 = *(const float4*)(vtp + 131072u + voff + i * 4);
                float4 pbv = *(const float4*)(pb + kc * 64 + vk + i * 4);
                float4 wv4;
                wv4.x = p0.x + p1.x + pbv.x; wv4.y = p0.y + p1.y + pbv.y;
                wv4.z = p0.z + p1.z + pbv.z; wv4.w = p0.w + p1.w + pbv.w;
                ssv += wv4.x * wv4.x + wv4.y * wv4.y + wv4.z * wv4.z + wv4.w * wv4.w;
                v_s[vl][vk + i * 4 + 0] = wv4.x; v_s[vl][vk + i * 4 + 1] = wv4.y;
                v_s[vl][vk + i * 4 + 2] = wv4.z; v_s[vl][vk + i * 4 + 3] = wv4.w;
            }
        }
        __syncthreads();
#pragma unroll 2
        for (int k = 0; k < 64; ++k) {
            float v0 = v_s[rg * 2 + 0][k];
            float v1 = v_s[rg * 2 + 1][k];
            float x0 = a_s[lg * 4 + 0][k];
            float x1 = a_s[lg * 4 + 1][k];
            float x2 = a_s[lg * 4 + 2][k];
            float x3 = a_s[lg * 4 + 3][k];
            c00 += v0 * x0; c01 += v0 * x1; c02 += v0 * x2; c03 += v0 * x3;
            c10 += v1 * x0; c11 += v1 * x1; c12 += v1 * x2; c13 += v1 * x3;
        }
    }
    ssa += __shfl_xor(ssa, 1); ssa += __shfl_xor(ssa, 2);
    if ((tid & 3) == 0) rinv_a[al] = rsqrtf(ssa);
    ssv += __shfl_xor(ssv, 1); ssv += __shfl_xor(ssv, 2); ssv += __shfl_xor(ssv, 4);
    if ((tid & 7) == 0) rinv_v[vl] = rsqrtf(ssv);
    __syncthreads();
    const float sc = __expf(ls[0]);
    const float bias = lb[0];
    float ra0 = rinv_a[lg * 4 + 0], ra1 = rinv_a[lg * 4 + 1];
    float ra2 = rinv_a[lg * 4 + 2], ra3 = rinv_a[lg * 4 + 3];
    float accs[2][4] = {{c00,c01,c02,c03},{c10,c11,c12,c13}};
#pragma unroll
    for (int cr = 0; cr < 2; ++cr) {
        int t = rg * 2 + cr;
        float rv = rinv_v[t] * sc;
        float4 o;
        o.x = accs[cr][0] * rv * ra0 + bias;
        o.y = accs[cr][1] * rv * ra1 + bias;
        o.z = accs[cr][2] * rv * ra2 + bias;
        o.w = accs[cr][3] * rv * ra3 + bias;
        *(float4*)(out + (size_t)b * 65536 + (size_t)t * 2048 + lc * 64 + lg * 4) = o;
    }
}

// ---------------- launch ----------------
extern "C" void kernel_launch(void* const* d_in, const int* in_sizes, int n_in,
                              void* d_out, int out_size, void* d_ws, size_t ws_size,
                              hipStream_t stream) {
    (void)in_sizes; (void)n_in; (void)out_size;
    const float* video = (const float*)d_in[0];
    const float* audio = (const float*)d_in[1];
    const float* probe = (const float*)d_in[2];
    const float* wq    = (const float*)d_in[3];
    const float* wk    = (const float*)d_in[4];
    const float* wv    = (const float*)d_in[5];
    const float* bq    = (const float*)d_in[6];
    const float* bk    = (const float*)d_in[7];
    const float* bv    = (const float*)d_in[8];
    const float* wo    = (const float*)d_in[9];
    const float* bo    = (const float*)d_in[10];
    const float* lng   = (const float*)d_in[11];
    const float* lnb   = (const float*)d_in[12];
    const float* pw    = (const float*)d_in[13];
    const float* pb    = (const float*)d_in[14];
    const float* ls    = (const float*)d_in[15];
    const float* lb    = (const float*)d_in[16];
    float* ws  = (float*)d_ws;
    float* out = (float*)d_out;
    if (ws_size < FB_FLOATS * sizeof(float)) return;

    float* qwt  = ws + FB_QWT;
    float* qbs  = ws + FB_QB;
    float* qf   = ws + FB_QF;
    float* ctxx = ws + FB_CTXX;
    float* ctxp = ws + FB_CTXP;
    float* poolp= ws + FB_POOLP;
    float* lno  = ws + FB_LNO;
    float* vtp  = ws + FB_VTP;

    k_qflat<<<dim3(1024), dim3(256), 0, stream>>>(probe, wq, bq, qf);
    k_qwt<<<dim3(16, 16), dim3(64), 0, stream>>>(qf, wk, bk, qwt, qbs);
    k1_attn<<<dim3(256), dim3(1024), 0, stream>>>(video, qwt, qbs, ctxx);
    // G1: ctxx (head-block diagonal) @ wv^T -> ctxp   [K=1024 split 2]
    k_gemm2<0><<<dim3(16, 16, 2), dim3(256), 0, stream>>>(ctxx, nullptr, nullptr, wv, ctxp,
                                                          16384u, 1024u, 1024u);
    // G2: (ctxp0+ctxp1+bv) @ wo^T -> poolp            [K=1024 split 2]
    k_gemm2<1><<<dim3(16, 16, 2), dim3(256), 0, stream>>>(ctxp, ctxp + 262144u, bv, wo, poolp,
                                                          1024u, 0u, 1024u);
    k_ln<<<dim3(256), dim3(256), 0, stream>>>(poolp, bo, lng, lnb, lno);
    // G3: lno @ pw^T -> vtp                           [K=1024 split 2]
    k_gemm2<0><<<dim3(16, 8, 2), dim3(256), 0, stream>>>(lno, nullptr, nullptr, pw, vtp,
                                                         1024u, 0u, 512u);
    k_sim<<<dim3(32, 8), dim3(256), 0, stream>>>(vtp, pb, audio, ls, lb, out);
}

// Round 10
// 296.462 us; speedup vs baseline: 1.0270x; 1.0270x over previous
//
#include <hip/hip_runtime.h>

// ---------------- problem constants ----------------
// B=8, T=32, S=256, DV=1024, NH=16, dh=64, DA=512, L2=2048
// video_x: [8, 8192, 1024] f32   audio_x: [8, 2048, 512] f32
// out: [8, 32, 2048] f32
//
// MEASURED (R3-R9):
//  * Two workgroups NEVER co-reside on a CU here (any LDS/VGPR size) ->
//    max concurrency = one 1024-thr block = 16 waves/CU.
//  * 1024-thr blocks get <=64 VGPR from the compiler regardless of
//    __launch_bounds__ -> any design with >64 live floats spills (R9:
//    193 MB spill writes). This k1 is engineered to ~50 live VGPRs:
//    query weights live in LDS (staged once, [h][d] layout), phase A is a
//    dual-LDS-source dot with 3 shuffles total (was 96/row in R9).
//
// Pipeline (all f32):
//  qf = probe@wqT+bq ; qwt_hd[h][d] = (1/8)*sum_{e in h} qf[e]*wk[e][d] ; qbs[h]
//  k1: per (b,t): p[s][h]=exp(x[s,:].qw[h,:]+qbs[h]); ctxx[h][d]=sum_s p*x /l
//  G1: ctx_part = ctxx(head-block) @ wv^T         (K-split 2 -> ctxp)
//  G2: pool_part = (ctxp0+ctxp1+bv) @ wo^T        (K-split 2 -> poolp)
//  LN: lno = LN(poolp0+poolp1+bo)
//  G3: vt_part = lno @ pw^T                       (K-split 2 -> vtp)
//  sim: (norm(vtp0+vtp1+pb) . norm(audio)) * exp(ls) + lb

// ---- ws layout (float offsets), 23.1 MB ----
#define FB_QWT    0u                       // [16][1024]  (h-major!)
#define FB_QB     16384u
#define FB_QF     16400u
#define FB_CTXX   18432u                   // [256][16][1024]
#define FB_CTXP   4212736u
#define FB_POOLP  4737024u
#define FB_LNO    5261312u
#define FB_VTP    5523456u
#define FB_FLOATS 5785600u

// ---------------- K0a: q_flat[e] = probe . wq[e,:] + bq[e] ----------------
__global__ __launch_bounds__(256) void k_qflat(const float* __restrict__ probe,
                                               const float* __restrict__ wq,
                                               const float* __restrict__ bq,
                                               float* __restrict__ qf) {
    int e = blockIdx.x, tid = threadIdx.x;
    const float* wr = wq + (size_t)e * 1024;
    float s = 0.f;
    for (int k = tid; k < 1024; k += 256) s += probe[k] * wr[k];
    s += __shfl_xor(s, 1);  s += __shfl_xor(s, 2);  s += __shfl_xor(s, 4);
    s += __shfl_xor(s, 8);  s += __shfl_xor(s, 16); s += __shfl_xor(s, 32);
    __shared__ float sm[4];
    if ((tid & 63) == 0) sm[tid >> 6] = s;
    __syncthreads();
    if (tid == 0) qf[e] = sm[0] + sm[1] + sm[2] + sm[3] + bq[e];
}

// ---------------- K0b: qwt_hd[h][d] = (1/8) * sum_{e in h} qf[e]*wk[e][d] ----------------
__global__ __launch_bounds__(64) void k_qwt(const float* __restrict__ qf,
                                            const float* __restrict__ wk,
                                            const float* __restrict__ bk,
                                            float* __restrict__ qwt_hd,
                                            float* __restrict__ qbs) {
    int kc = blockIdx.x, h = blockIdx.y, tid = threadIdx.x; // 64 threads = 1 wave
    int d = kc * 64 + tid;
    float s = 0.f;
    for (int e0 = 0; e0 < 64; ++e0) {
        int e = h * 64 + e0;
        s += qf[e] * wk[(size_t)e * 1024 + d];
    }
    qwt_hd[h * 1024 + d] = s * 0.125f;      // h-major layout for k1 LDS staging
    if (kc == 0) {
        float p = qf[h * 64 + tid] * bk[h * 64 + tid];
        p += __shfl_xor(p, 1);  p += __shfl_xor(p, 2);  p += __shfl_xor(p, 4);
        p += __shfl_xor(p, 8);  p += __shfl_xor(p, 16); p += __shfl_xor(p, 32);
        if (tid == 0) qbs[h] = p * 0.125f;
    }
}

// ---------------- K1: low-VGPR fused scores+softmax+ctxx ----------------
// 1024 threads (16 waves), one (b,t) per block, 8-row chunks, dbuf LDS.
// Phase A: thread=(r=t>>7, h=(t>>3)&15, oct=t&7): 128-d partial dot, both
//   operands from LDS (x broadcast over h; bank-rotated kk=(k+oct)&31 so the
//   8 octs hit 8 distinct bank-groups), 3-shuffle reduce, exp by oct==0.
// Phase C: thread=(hq=t>>8, c4=t&255): acc[4]xfloat4, p broadcast from LDS.
// Live VGPRs ~50 (st 8 + acc 16 + temps) -- under the 64-VGPR cliff.
__global__ __launch_bounds__(1024, 1) void k1_attn(const float* __restrict__ x,
                                                   const float* __restrict__ qwt_hd,
                                                   const float* __restrict__ qbs,
                                                   float* __restrict__ ctxx) {
    __shared__ __align__(16) float xs[2][8][1024];   // 64 KB
    __shared__ __align__(16) float qws[16][1024];    // 64 KB, [h][d]
    __shared__ __align__(16) float p_lds[8][16];
    __shared__ float qb_lds[16];
    __shared__ float lp_lds[8][16];
    __shared__ float linv_lds[16];

    const int tid = threadIdx.x;
    const int r   = tid >> 7;           // phase A row 0..7
    const int h   = (tid >> 3) & 15;    // phase A head
    const int oct = tid & 7;            // phase A d-octant
    const int hq  = tid >> 8;           // phase C head-quartet 0..3
    const int c4  = tid & 255;          // phase C float4 column
    const int bt  = blockIdx.x;
    const float* xb = x + (size_t)bt * 262144;

    // stage qwt_hd -> qws (linear float4 copy), qbs -> qb_lds
    {
        const float4* src = (const float4*)qwt_hd;
        float4* dst = (float4*)&qws[0][0];
#pragma unroll
        for (int i = 0; i < 4; ++i) dst[tid + i * 1024] = src[tid + i * 1024];
        if (tid < 16) qb_lds[tid] = qbs[tid];
    }

    float lreg = 0.f;
    float4 acc[4];
#pragma unroll
    for (int i = 0; i < 4; ++i) acc[i] = make_float4(0.f, 0.f, 0.f, 0.f);

    // prologue: chunk 0 (8 rows = 2048 float4), 2 f4/thread
    float4 st[2];
#pragma unroll
    for (int i = 0; i < 2; ++i)
        st[i] = *(const float4*)(xb + (size_t)(tid + i * 1024) * 4);

    for (int c = 0; c < 32; ++c) {
        const int cur = c & 1;
        float4* xw = (float4*)&xs[cur][0][0];
#pragma unroll
        for (int i = 0; i < 2; ++i) xw[tid + i * 1024] = st[i];
        __syncthreads();                  // (1) xs[cur]+qws ready; prev C done
        if (c < 31) {                     // prefetch next chunk during compute
            const float* nb = xb + (size_t)(c + 1) * 8192;
#pragma unroll
            for (int i = 0; i < 2; ++i)
                st[i] = *(const float4*)(nb + (size_t)(tid + i * 1024) * 4);
        }
        // ---- phase A: scores ----
        {
            const float* xr = &xs[cur][r][0];
            const float* qr = &qws[h][0];
            float s = 0.f;
#pragma unroll
            for (int k = 0; k < 32; ++k) {
                const int kk = (k + oct) & 31;        // bank-group rotation
                const int d = oct * 128 + kk * 4;
                float4 xv = *(const float4*)&xr[d];
                float4 qv = *(const float4*)&qr[d];
                s += xv.x * qv.x + xv.y * qv.y + xv.z * qv.z + xv.w * qv.w;
            }
            s += __shfl_xor(s, 1); s += __shfl_xor(s, 2); s += __shfl_xor(s, 4);
            if (oct == 0) {
                // scores ~|0.05| -> exp with shift 0 numerically safe here
                float pv = __expf(s + qb_lds[h]);
                p_lds[r][h] = pv;
                lreg += pv;
            }
        }
        __syncthreads();                  // (2) p_lds ready
        // ---- phase C: thread = 1 float4 column x 4 heads, 8 rows ----
#pragma unroll
        for (int rr = 0; rr < 8; ++rr) {
            float4 xv = *(const float4*)&xs[cur][rr][c4 * 4];
            float4 p4 = *(const float4*)&p_lds[rr][hq * 4];
            acc[0].x += p4.x * xv.x; acc[0].y += p4.x * xv.y; acc[0].z += p4.x * xv.z; acc[0].w += p4.x * xv.w;
            acc[1].x += p4.y * xv.x; acc[1].y += p4.y * xv.y; acc[1].z += p4.y * xv.z; acc[1].w += p4.y * xv.w;
            acc[2].x += p4.z * xv.x; acc[2].y += p4.z * xv.y; acc[2].z += p4.z * xv.z; acc[2].w += p4.z * xv.w;
            acc[3].x += p4.w * xv.x; acc[3].y += p4.w * xv.y; acc[3].z += p4.w * xv.z; acc[3].w += p4.w * xv.w;
        }
    }

    if (oct == 0) lp_lds[r][h] = lreg;
    __syncthreads();
    if (tid < 16) {
        float l = 0.f;
#pragma unroll
        for (int rr = 0; rr < 8; ++rr) l += lp_lds[rr][tid];
        linv_lds[tid] = 1.0f / l;
    }
    __syncthreads();
    float* ob = ctxx + (size_t)bt * 16384;
#pragma unroll
    for (int i = 0; i < 4; ++i) {
        float li = linv_lds[hq * 4 + i];
        float4 o = acc[i];
        o.x *= li; o.y *= li; o.z *= li; o.w *= li;
        *(float4*)(ob + (hq * 4 + i) * 1024 + c4 * 4) = o;
    }
}

// ---------------- K-split GEMM: outp[ks][r][e] = A_row(r)[koff:+512] . B[e, koff:+512] ----
// tile 16 rows x 64 cols, 256 threads, K-slice 512 (8 kc-steps of 64).
// FOLD=0: A_eff = A0
// FOLD=1: A_eff = A0 + A1 + biask (K-dim bias folded)
template<int FOLD>
__global__ __launch_bounds__(256, 2) void k_gemm2(const float* __restrict__ A0,
                                                  const float* __restrict__ A1,
                                                  const float* __restrict__ biask,
                                                  const float* __restrict__ Bw,
                                                  float* __restrict__ outp,
                                                  unsigned a_rstride, unsigned a_cstride,
                                                  unsigned ostride) {
    __shared__ __align__(16) float a_s[16][68];
    __shared__ __align__(16) float b_s[64][68];   // col-f4 swizzled: cs=(k4+e/4)&15
    const int tid = threadIdx.x;
    const int rc = blockIdx.x;     // row-chunk (16 rows)
    const int cb = blockIdx.y;     // col-block (64 cols)
    const int ks = blockIdx.z;     // K-split 0,1
    const int koff = ks * 512;
    const int rr = tid >> 4;       // output row 0..15
    const int ee = tid & 15;       // output cols ee*4..+3

    const size_t abase = (size_t)(rc * 16 + rr) * a_rstride + (size_t)cb * a_cstride + koff;

    float ac0 = 0.f, ac1 = 0.f, ac2 = 0.f, ac3 = 0.f;

    for (int kc = 0; kc < 8; ++kc) {
        __syncthreads();
        {   // stage A: 1 float4/thread
            float4 av = *(const float4*)(A0 + abase + kc * 64 + ee * 4);
            if (FOLD == 1) {
                float4 a1 = *(const float4*)(A1 + abase + kc * 64 + ee * 4);
                float4 bk4 = *(const float4*)(biask + koff + kc * 64 + ee * 4);
                av.x += a1.x + bk4.x; av.y += a1.y + bk4.y;
                av.z += a1.z + bk4.z; av.w += a1.w + bk4.w;
            }
            *(float4*)&a_s[rr][ee * 4] = av;
        }
        // stage B: 4 float4/thread, linear global -> swizzled LDS
#pragma unroll
        for (int i = 0; i < 4; ++i) {
            int f4i = tid + i * 256;
            int e = f4i >> 4, k4 = f4i & 15;
            float4 bv4 = *(const float4*)(Bw + (size_t)(cb * 64 + e) * 1024 + koff + kc * 64 + k4 * 4);
            int cs = (k4 + (e >> 2)) & 15;
            *(float4*)&b_s[e][cs * 4] = bv4;
        }
        __syncthreads();
#pragma unroll
        for (int k4 = 0; k4 < 16; ++k4) {
            float4 av = *(const float4*)&a_s[rr][k4 * 4];
            int cs = (k4 + ee) & 15;
            float4 b0 = *(const float4*)&b_s[ee * 4 + 0][cs * 4];
            float4 b1 = *(const float4*)&b_s[ee * 4 + 1][cs * 4];
            float4 b2 = *(const float4*)&b_s[ee * 4 + 2][cs * 4];
            float4 b3 = *(const float4*)&b_s[ee * 4 + 3][cs * 4];
            ac0 += av.x * b0.x + av.y * b0.y + av.z * b0.z + av.w * b0.w;
            ac1 += av.x * b1.x + av.y * b1.y + av.z * b1.z + av.w * b1.w;
            ac2 += av.x * b2.x + av.y * b2.y + av.z * b2.z + av.w * b2.w;
            ac3 += av.x * b3.x + av.y * b3.y + av.z * b3.z + av.w * b3.w;
        }
    }
    float4 o = make_float4(ac0, ac1, ac2, ac3);
    *(float4*)(outp + (size_t)ks * 256 * ostride + (size_t)(rc * 16 + rr) * ostride + cb * 64 + ee * 4) = o;
}

// ---------------- LayerNorm over D=1024, folds poolp0+poolp1+bo ----------------
__global__ __launch_bounds__(256) void k_ln(const float* __restrict__ poolp,
                                            const float* __restrict__ bo,
                                            const float* __restrict__ g,
                                            const float* __restrict__ bb,
                                            float* __restrict__ out) {
    __shared__ float sm[8];
    int row = blockIdx.x, tid = threadIdx.x;
    float4 v0 = *(const float4*)(poolp + (size_t)row * 1024 + tid * 4);
    float4 v1 = *(const float4*)(poolp + 262144u + (size_t)row * 1024 + tid * 4);
    float4 bv = *(const float4*)(bo + tid * 4);
    float4 v;
    v.x = v0.x + v1.x + bv.x; v.y = v0.y + v1.y + bv.y;
    v.z = v0.z + v1.z + bv.z; v.w = v0.w + v1.w + bv.w;
    float s = v.x + v.y + v.z + v.w;
    float q = v.x * v.x + v.y * v.y + v.z * v.z + v.w * v.w;
    s += __shfl_xor(s, 1);  q += __shfl_xor(q, 1);
    s += __shfl_xor(s, 2);  q += __shfl_xor(q, 2);
    s += __shfl_xor(s, 4);  q += __shfl_xor(q, 4);
    s += __shfl_xor(s, 8);  q += __shfl_xor(q, 8);
    s += __shfl_xor(s, 16); q += __shfl_xor(q, 16);
    s += __shfl_xor(s, 32); q += __shfl_xor(q, 32);
    if ((tid & 63) == 0) { sm[tid >> 6] = s; sm[4 + (tid >> 6)] = q; }
    __syncthreads();
    float S = sm[0] + sm[1] + sm[2] + sm[3];
    float Q = sm[4] + sm[5] + sm[6] + sm[7];
    float mu = S * (1.f / 1024.f);
    float var = Q * (1.f / 1024.f) - mu * mu;
    float rs = rsqrtf(var + 1e-6f);
    float4 gg = *(const float4*)(g + tid * 4);
    float4 be = *(const float4*)(bb + tid * 4);
    float4 o;
    o.x = (v.x - mu) * rs * gg.x + be.x;
    o.y = (v.y - mu) * rs * gg.y + be.y;
    o.z = (v.z - mu) * rs * gg.z + be.z;
    o.w = (v.w - mu) * rs * gg.w + be.w;
    *(float4*)(out + (size_t)row * 1024 + tid * 4) = o;
}

// ---------------- sim = (vt_hat . a_hat) * exp(ls) + lb ----------------
// folds vtp0+vtp1+pb; block: 32 vt rows x 64 audio rows; grid (32,8)
__global__ __launch_bounds__(256, 2) void k_sim(const float* __restrict__ vtp,
                                                const float* __restrict__ pb,
                                                const float* __restrict__ audio,
                                                const float* __restrict__ ls,
                                                const float* __restrict__ lb,
                                                float* __restrict__ out) {
    __shared__ float a_s[64][65];
    __shared__ float v_s[32][65];
    __shared__ float rinv_a[64];
    __shared__ float rinv_v[32];
    const int tid = threadIdx.x;
    const int lc = blockIdx.x;   // 0..31
    const int b  = blockIdx.y;   // 0..7
    const int al = tid >> 2, ak = (tid & 3) * 16;
    const int vl = tid >> 3, vk = (tid & 7) * 8;
    const int rg = tid >> 4, lg = tid & 15;
    float ssa = 0.f, ssv = 0.f;
    float c00=0,c01=0,c02=0,c03=0,c10=0,c11=0,c12=0,c13=0;

    for (int kc = 0; kc < 8; ++kc) {
        __syncthreads();
        {
            const float* ap = audio + (size_t)b * 1048576 + (size_t)(lc * 64 + al) * 512 + kc * 64 + ak;
#pragma unroll
            for (int i = 0; i < 4; ++i) {
                float4 wv4 = *(const float4*)(ap + i * 4);
                ssa += wv4.x * wv4.x + wv4.y * wv4.y + wv4.z * wv4.z + wv4.w * wv4.w;
                a_s[al][ak + i * 4 + 0] = wv4.x; a_s[al][ak + i * 4 + 1] = wv4.y;
                a_s[al][ak + i * 4 + 2] = wv4.z; a_s[al][ak + i * 4 + 3] = wv4.w;
            }
            const size_t voff = (size_t)(b * 32 + vl) * 512 + kc * 64 + vk;
#pragma unroll
            for (int i = 0; i < 2; ++i) {
                float4 p0 = *(const float4*)(vtp + voff + i * 4);
                float4 p1 = *(const float4*)(vtp + 131072u + voff + i * 4);
                float4 pbv = *(const float4*)(pb + kc * 64 + vk + i * 4);
                float4 wv4;
                wv4.x = p0.x + p1.x + pbv.x; wv4.y = p0.y + p1.y + pbv.y;
                wv4.z = p0.z + p1.z + pbv.z; wv4.w = p0.w + p1.w + pbv.w;
                ssv += wv4.x * wv4.x + wv4.y * wv4.y + wv4.z * wv4.z + wv4.w * wv4.w;
                v_s[vl][vk + i * 4 + 0] = wv4.x; v_s[vl][vk + i * 4 + 1] = wv4.y;
                v_s[vl][vk + i * 4 + 2] = wv4.z; v_s[vl][vk + i * 4 + 3] = wv4.w;
            }
        }
        __syncthreads();
#pragma unroll 2
        for (int k = 0; k < 64; ++k) {
            float v0 = v_s[rg * 2 + 0][k];
            float v1 = v_s[rg * 2 + 1][k];
            float x0 = a_s[lg * 4 + 0][k];
            float x1 = a_s[lg * 4 + 1][k];
            float x2 = a_s[lg * 4 + 2][k];
            float x3 = a_s[lg * 4 + 3][k];
            c00 += v0 * x0; c01 += v0 * x1; c02 += v0 * x2; c03 += v0 * x3;
            c10 += v1 * x0; c11 += v1 * x1; c12 += v1 * x2; c13 += v1 * x3;
        }
    }
    ssa += __shfl_xor(ssa, 1); ssa += __shfl_xor(ssa, 2);
    if ((tid & 3) == 0) rinv_a[al] = rsqrtf(ssa);
    ssv += __shfl_xor(ssv, 1); ssv += __shfl_xor(ssv, 2); ssv += __shfl_xor(ssv, 4);
    if ((tid & 7) == 0) rinv_v[vl] = rsqrtf(ssv);
    __syncthreads();
    const float sc = __expf(ls[0]);
    const float bias = lb[0];
    float ra0 = rinv_a[lg * 4 + 0], ra1 = rinv_a[lg * 4 + 1];
    float ra2 = rinv_a[lg * 4 + 2], ra3 = rinv_a[lg * 4 + 3];
    float accs[2][4] = {{c00,c01,c02,c03},{c10,c11,c12,c13}};
#pragma unroll
    for (int cr = 0; cr < 2; ++cr) {
        int t = rg * 2 + cr;
        float rv = rinv_v[t] * sc;
        float4 o;
        o.x = accs[cr][0] * rv * ra0 + bias;
        o.y = accs[cr][1] * rv * ra1 + bias;
        o.z = accs[cr][2] * rv * ra2 + bias;
        o.w = accs[cr][3] * rv * ra3 + bias;
        *(float4*)(out + (size_t)b * 65536 + (size_t)t * 2048 + lc * 64 + lg * 4) = o;
    }
}

// ---------------- launch ----------------
extern "C" void kernel_launch(void* const* d_in, const int* in_sizes, int n_in,
                              void* d_out, int out_size, void* d_ws, size_t ws_size,
                              hipStream_t stream) {
    (void)in_sizes; (void)n_in; (void)out_size;
    const float* video = (const float*)d_in[0];
    const float* audio = (const float*)d_in[1];
    const float* probe = (const float*)d_in[2];
    const float* wq    = (const float*)d_in[3];
    const float* wk    = (const float*)d_in[4];
    const float* wv    = (const float*)d_in[5];
    const float* bq    = (const float*)d_in[6];
    const float* bk    = (const float*)d_in[7];
    const float* bv    = (const float*)d_in[8];
    const float* wo    = (const float*)d_in[9];
    const float* bo    = (const float*)d_in[10];
    const float* lng   = (const float*)d_in[11];
    const float* lnb   = (const float*)d_in[12];
    const float* pw    = (const float*)d_in[13];
    const float* pb    = (const float*)d_in[14];
    const float* ls    = (const float*)d_in[15];
    const float* lb    = (const float*)d_in[16];
    float* ws  = (float*)d_ws;
    float* out = (float*)d_out;
    if (ws_size < FB_FLOATS * sizeof(float)) return;

    float* qwt  = ws + FB_QWT;   // [16][1024] h-major
    float* qbs  = ws + FB_QB;
    float* qf   = ws + FB_QF;
    float* ctxx = ws + FB_CTXX;
    float* ctxp = ws + FB_CTXP;
    float* poolp= ws + FB_POOLP;
    float* lno  = ws + FB_LNO;
    float* vtp  = ws + FB_VTP;

    k_qflat<<<dim3(1024), dim3(256), 0, stream>>>(probe, wq, bq, qf);
    k_qwt<<<dim3(16, 16), dim3(64), 0, stream>>>(qf, wk, bk, qwt, qbs);
    k1_attn<<<dim3(256), dim3(1024), 0, stream>>>(video, qwt, qbs, ctxx);
    // G1: ctxx (head-block diagonal) @ wv^T -> ctxp   [K=1024 split 2]
    k_gemm2<0><<<dim3(16, 16, 2), dim3(256), 0, stream>>>(ctxx, nullptr, nullptr, wv, ctxp,
                                                          16384u, 1024u, 1024u);
    // G2: (ctxp0+ctxp1+bv) @ wo^T -> poolp            [K=1024 split 2]
    k_gemm2<1><<<dim3(16, 16, 2), dim3(256), 0, stream>>>(ctxp, ctxp + 262144u, bv, wo, poolp,
                                                          1024u, 0u, 1024u);
    k_ln<<<dim3(256), dim3(256), 0, stream>>>(poolp, bo, lng, lnb, lno);
    // G3: lno @ pw^T -> vtp                           [K=1024 split 2]
    k_gemm2<0><<<dim3(16, 8, 2), dim3(256), 0, stream>>>(lno, nullptr, nullptr, pw, vtp,
                                                         1024u, 0u, 512u);
    k_sim<<<dim3(32, 8), dim3(256), 0, stream>>>(vtp, pb, audio, ls, lb, out);
}